// Round 1
// baseline (381.932 us; speedup 1.0000x reference)
//
#include <hip/hip_runtime.h>
#include <cstdint>
#include <cstddef>

#define N 1024
#define HN 4
#define FDIM 64
#define FLT_MAX_ 3.402823466e+38f

// ---------------- reduction helpers (blockDim.x == 256) ----------------
__device__ __forceinline__ float wred_sum(float v){
#pragma unroll
  for(int o=32;o>0;o>>=1) v += __shfl_down(v,o,64);
  return v;
}
__device__ __forceinline__ float wred_max(float v){
#pragma unroll
  for(int o=32;o>0;o>>=1) v = fmaxf(v,__shfl_down(v,o,64));
  return v;
}
__device__ __forceinline__ float bred_sum(float v, float* scr){
  int t=threadIdx.x;
  v = wred_sum(v);
  __syncthreads();
  if((t&63)==0) scr[t>>6]=v;
  __syncthreads();
  return (scr[0]+scr[1])+(scr[2]+scr[3]);
}
__device__ __forceinline__ float bred_max(float v, float* scr){
  int t=threadIdx.x;
  v = wred_max(v);
  __syncthreads();
  if((t&63)==0) scr[t>>6]=v;
  __syncthreads();
  return fmaxf(fmaxf(scr[0],scr[1]),fmaxf(scr[2],scr[3]));
}

// ---------------- K0: zero masks ----------------
__global__ __launch_bounds__(256) void zero_ints(int* p, int n){
  int i = blockIdx.x*256 + threadIdx.x;
  if(i<n) p[i]=0;
}

// ---------------- K1: g_l = x@W_l, g_r = x@W_r  (x:[N,256], W:[256,256]) ----------------
__global__ __launch_bounds__(256) void gemm_lr(const float* __restrict__ x,
                                               const float* __restrict__ W_l,
                                               const float* __restrict__ W_r,
                                               float* __restrict__ g_l,
                                               float* __restrict__ g_r){
  __shared__ float xs[8][256];
  int i0 = blockIdx.x*8, t = threadIdx.x;
#pragma unroll
  for(int k=0;k<8;k++){
    int idx = t + k*256;
    xs[idx>>8][idx&255] = x[(size_t)(i0 + (idx>>8))*256 + (idx&255)];
  }
  __syncthreads();
  float accL[8], accR[8];
#pragma unroll
  for(int r=0;r<8;r++){ accL[r]=0.f; accR[r]=0.f; }
  for(int k=0;k<256;k++){
    float wl = W_l[(size_t)k*256 + t];
    float wr = W_r[(size_t)k*256 + t];
#pragma unroll
    for(int r=0;r<8;r++){
      accL[r] = fmaf(xs[r][k], wl, accL[r]);
      accR[r] = fmaf(xs[r][k], wr, accR[r]);
    }
  }
#pragma unroll
  for(int r=0;r<8;r++){
    g_l[(size_t)(i0+r)*256 + t] = accL[r];
    g_r[(size_t)(i0+r)*256 + t] = accR[r];
  }
}

// ---------------- K2p: partial column min/max (16 row-chunks) ----------------
// blockIdx.x = chunk (0..15), blockIdx.y = src (0: feats cols=128, 1: g_r cols=256)
__global__ __launch_bounds__(256) void colmm_part(const float* __restrict__ feats,
                                                  const float* __restrict__ g_r,
                                                  float* __restrict__ pmin_f, float* __restrict__ pmax_f,
                                                  float* __restrict__ pmin_g, float* __restrict__ pmax_g){
  int chunk = blockIdx.x, src = blockIdx.y, t = threadIdx.x;
  int cols = src ? 256 : 128;
  const float* in = src ? g_r : feats;
  if(t < cols){
    float lo = FLT_MAX_, hi = -FLT_MAX_;
    int r0 = chunk*64;
    for(int r=0;r<64;r++){
      float v = in[(size_t)(r0+r)*cols + t];
      lo = fminf(lo,v); hi = fmaxf(hi,v);
    }
    if(src){ pmin_g[chunk*256+t]=lo; pmax_g[chunk*256+t]=hi; }
    else   { pmin_f[chunk*128+t]=lo; pmax_f[chunk*128+t]=hi; }
  }
}

// ---------------- K2f: finalize min/max ----------------
__global__ __launch_bounds__(256) void colmm_fin(const float* __restrict__ pmin_f, const float* __restrict__ pmax_f,
                                                 const float* __restrict__ pmin_g, const float* __restrict__ pmax_g,
                                                 float* __restrict__ fmn, float* __restrict__ fmx,
                                                 float* __restrict__ gmn, float* __restrict__ gmx){
  int src = blockIdx.x, t = threadIdx.x;
  int cols = src ? 256 : 128;
  if(t < cols){
    float lo = FLT_MAX_, hi = -FLT_MAX_;
    const float* pn = src ? pmin_g : pmin_f;
    const float* px = src ? pmax_g : pmax_f;
    for(int k=0;k<16;k++){
      lo = fminf(lo, pn[k*cols+t]);
      hi = fmaxf(hi, px[k*cols+t]);
    }
    if(src){ gmn[t]=lo; gmx[t]=hi; } else { fmn[t]=lo; fmx[t]=hi; }
  }
}

// ---------------- K2n: nf (z=0) and ng (z=1) norms ----------------
__global__ __launch_bounds__(256) void norms_kernel(const float* __restrict__ feats,
                                                    const float* __restrict__ g_r,
                                                    const float* __restrict__ fmn, const float* __restrict__ fmx,
                                                    const float* __restrict__ gmn, const float* __restrict__ gmx,
                                                    float* __restrict__ nf, float* __restrict__ ng){
  __shared__ float scr[4];
  int i = blockIdx.x, z = blockIdx.y, t = threadIdx.x;
  if(z==0){
    float u = 0.f;
    if(t < 128){
      float d = fmx[t]-fmn[t];
      float v = feats[(size_t)i*128 + t];
      u = (d==0.f) ? 0.f : (v - fmn[t])/d;   // matches fn nan-guard
    }
    float tot = bred_sum(u*u, scr);
    if(t==0) nf[i] = sqrtf(tot);
  } else {
    int c = t, hh = t>>6;
    float d = gmx[c]-gmn[c];
    float v = g_r[(size_t)i*256 + c];
    float u = (v - gmn[c])/d;               // reference has no guard here
    float ss = wred_sum(u*u);
    if((t&63)==0) ng[hh*N + i] = sqrtf(ss);
  }
}

// ---------------- K3: e[h][i][j] = sum_f leaky(g_r[i,h,f]+g_l[j,h,f]) * w[f] ----------------
// grid (16,16,4): x=jt, y=it, z=h ; 64x64 tile, 4x4 per thread
__global__ __launch_bounds__(256) void compute_e(const float* __restrict__ g_l,
                                                 const float* __restrict__ g_r,
                                                 const float* __restrict__ attn_w,
                                                 float* __restrict__ e){
  __shared__ float grs[64][65];
  __shared__ float gls[64][65];
  __shared__ float aw[64], aw2[64];
  int h = blockIdx.z, i0 = blockIdx.y*64, j0 = blockIdx.x*64;
  int t = threadIdx.x;
  if(t < 64){ float w = attn_w[t]; aw[t]=w; aw2[t]=0.2f*w; }
#pragma unroll
  for(int k=0;k<16;k++){
    int idx = t + k*256; int r = idx>>6, f = idx&63;
    grs[r][f] = g_r[(size_t)(i0+r)*256 + h*64 + f];
    gls[r][f] = g_l[(size_t)(j0+r)*256 + h*64 + f];
  }
  __syncthreads();
  int tj = t&15, ti = t>>4;       // 16 x 16 thread grid
  float acc[4][4];
#pragma unroll
  for(int a=0;a<4;a++)
#pragma unroll
    for(int b=0;b<4;b++) acc[a][b]=0.f;
  for(int f=0;f<64;f++){
    float w = aw[f], w2 = aw2[f];
    float ga[4], gb[4];
#pragma unroll
    for(int a=0;a<4;a++) ga[a] = grs[ti*4+a][f];
#pragma unroll
    for(int b=0;b<4;b++) gb[b] = gls[tj+16*b][f];
#pragma unroll
    for(int a=0;a<4;a++)
#pragma unroll
      for(int b=0;b<4;b++){
        float s = ga[a]+gb[b];
        float ws = (s >= 0.f) ? w : w2;
        acc[a][b] = fmaf(s, ws, acc[a][b]);
      }
  }
#pragma unroll
  for(int a=0;a<4;a++)
#pragma unroll
    for(int b=0;b<4;b++){
      int i = i0 + ti*4 + a, j = j0 + tj + 16*b;
      e[((size_t)h*N + i)*N + j] = acc[a][b];
    }
}

// ---------------- K4: per-(h,i) row fusion ----------------
// reads e row, writes a_1nd over e, writes gamma, stores m_g/s_g
__global__ __launch_bounds__(256) void row_kernel(float* __restrict__ e,
                                                  float* __restrict__ gam,
                                                  const int* __restrict__ adj,
                                                  const float* __restrict__ nf,
                                                  const float* __restrict__ ng,
                                                  float* __restrict__ mgA,
                                                  float* __restrict__ sgA){
  __shared__ float es[1024];
  __shared__ float nfs[1024];
  __shared__ unsigned char adjs[1024];
  __shared__ float scr[4];
  int i = blockIdx.x, h = blockIdx.y, t = threadIdx.x;
  size_t base = ((size_t)h*N + i)*N;
  float ngv = ng[h*N + i];
#pragma unroll
  for(int k=0;k<4;k++){
    int j = t + k*256;
    es[j]  = e[base + j];
    nfs[j] = nf[j];
    adjs[j] = (adj[(size_t)i*N + j] > 0) ? 1 : 0;
  }
  __syncthreads();
  float ml=-FLT_MAX_, mo=-FLT_MAX_, ma=-FLT_MAX_;
#pragma unroll
  for(int k=0;k<4;k++){
    int j = t + k*256;
    float ev = es[j];
    mo = fmaxf(mo, ev);
    if(adjs[j]) ml = fmaxf(ml, ev);
    ma = fmaxf(ma, fabsf(nfs[j]-ngv));
  }
  ml = bred_max(ml, scr); mo = bred_max(mo, scr); ma = bred_max(ma, scr);
  float sl=0.f, so=0.f, sa=0.f;
#pragma unroll
  for(int k=0;k<4;k++){
    int j = t + k*256;
    float ev = es[j];
    so += __expf(ev-mo);
    if(adjs[j]) sl += __expf(ev-ml);
    sa += __expf(fabsf(nfs[j]-ngv)-ma);
  }
  sl = bred_sum(sl, scr); so = bred_sum(so, scr); sa = bred_sum(sa, scr);
  float isl = 1.f/sl, iso = 1.f/so, isa = 1.f/sa;
  float mg = -FLT_MAX_;
  float gloc[4];
#pragma unroll
  for(int k=0;k<4;k++){
    int j = t + k*256;
    float ev = es[j];
    float omega = __expf(ev-mo)*iso;
    float alpha = __expf(fabsf(nfs[j]-ngv)-ma)*isa;
    float g = 0.5f*(omega + 1.f - alpha);
    gloc[k] = g;
    gam[base+j] = g;
    float a1 = adjs[j] ? __expf(ev-ml)*isl : 0.f;
    e[base+j] = a1;
    mg = fmaxf(mg, g);
  }
  mg = bred_max(mg, scr);
  float sg = 0.f;
#pragma unroll
  for(int k=0;k<4;k++) sg += __expf((gloc[k]-mg)/1e-3f);
  sg = bred_sum(sg, scr);
  if(t==0){ mgA[h*N+i]=mg; sgA[h*N+i]=sg; }
}

// ---------------- K5: exact top-512 column select -> row-union mask ----------------
// grid (N, HN); arr layout [h][i][j]; mask[h*N + i] = 1 if selected in any column
__global__ __launch_bounds__(256) void colselect(const float* __restrict__ arr,
                                                 int* __restrict__ mask){
  __shared__ unsigned int vals[1024];
  __shared__ int hist[256];
  __shared__ int sscan[256];
  __shared__ int bsel, knew, totgt;
  int j = blockIdx.x, h = blockIdx.y, t = threadIdx.x;
  size_t base = ((size_t)h*N)*(size_t)N + j;
#pragma unroll
  for(int q=0;q<4;q++){
    int i = 4*t + q;
    vals[i] = __float_as_uint(arr[base + (size_t)i*N]);  // values >= 0 -> monotone bits
  }
  if(t==0) totgt = 0;
  __syncthreads();
  unsigned prefix = 0; int kth = 512;
  for(int b=3;b>=0;b--){
    hist[t] = 0;
    __syncthreads();
#pragma unroll
    for(int q=0;q<4;q++){
      unsigned u = vals[4*t+q];
      bool act = (b==3) || ((u >> (8*(b+1))) == prefix);
      if(act) atomicAdd(&hist[(u >> (8*b)) & 0xFF], 1);
    }
    __syncthreads();
    sscan[t] = hist[t];
    __syncthreads();
    for(int off=1; off<256; off<<=1){          // inclusive suffix scan
      int v2 = (t+off < 256) ? sscan[t+off] : 0;
      __syncthreads();
      sscan[t] += v2;
      __syncthreads();
    }
    int ge_t  = sscan[t];
    int ge_t1 = ge_t - hist[t];
    if(ge_t >= kth && ge_t1 < kth){ bsel = t; knew = kth - ge_t1; }
    __syncthreads();
    prefix = (prefix << 8) | (unsigned)bsel;
    kth = knew;
    __syncthreads();
  }
  unsigned T = prefix;
  int cg = 0, tc = 0;
#pragma unroll
  for(int q=0;q<4;q++){
    unsigned u = vals[4*t+q];
    cg += (u > T) ? 1 : 0;
    tc += (u == T) ? 1 : 0;
  }
  atomicAdd(&totgt, cg);
  sscan[t] = tc;
  __syncthreads();
  for(int off=1; off<256; off<<=1){            // inclusive prefix scan (index order)
    int v2 = (t >= off) ? sscan[t-off] : 0;
    __syncthreads();
    sscan[t] += v2;
    __syncthreads();
  }
  int tie_excl = sscan[t] - tc;
  __syncthreads();
  int tneed = 512 - totgt;
  int run = tie_excl;
#pragma unroll
  for(int q=0;q<4;q++){
    int i = 4*t+q;
    unsigned u = vals[i];
    bool sel = (u > T);
    if(u == T){ if(run < tneed) sel = true; run++; }
    if(sel) mask[h*N + i] = 1;
  }
}

// ---------------- K6: attn_local / attn_global partial matmuls ----------------
// grid (8, 4, 8): x = i-tile(128 rows), y = h, z = j-split (128 cols of j)
__global__ __launch_bounds__(256) void attn_mm(const float* __restrict__ a1nd,
                                               const float* __restrict__ gam,
                                               const float* __restrict__ g_r,
                                               const float* __restrict__ mgA,
                                               const float* __restrict__ sgA,
                                               const int* __restrict__ mask_g,
                                               float* __restrict__ partL,
                                               float* __restrict__ partG){
  __shared__ __align__(16) float a_s[128][33];
  __shared__ __align__(16) float p_s[128][33];
  __shared__ __align__(16) float b_s[32][64];
  __shared__ float mgv[128], isg[128];
  __shared__ int   mgf[128];
  int i0 = blockIdx.x*128, h = blockIdx.y, s = blockIdx.z, j0 = s*128;
  int t = threadIdx.x;
  if(t < 128){
    mgv[t] = mgA[h*N + i0 + t];
    isg[t] = 1.f / sgA[h*N + i0 + t];
    mgf[t] = mask_g[h*N + i0 + t];
  }
  __syncthreads();
  int fq = t & 15, iq = t >> 4;
  float4 accL[8], accG[8];
#pragma unroll
  for(int r=0;r<8;r++){ accL[r]=make_float4(0,0,0,0); accG[r]=make_float4(0,0,0,0); }
  for(int sub=0; sub<4; sub++){
    int jb = j0 + sub*32;
#pragma unroll
    for(int k=0;k<16;k++){
      int idx = t + k*256; int ii = idx>>5, jj = idx&31;
      size_t g = ((size_t)h*N + i0+ii)*N + jb + jj;
      a_s[ii][jj] = a1nd[g];
      float gm = gam[g];
      p_s[ii][jj] = mgf[ii] ? __expf((gm - mgv[ii])/1e-3f)*isg[ii] : (1.f/1024.f);
    }
#pragma unroll
    for(int k=0;k<8;k++){
      int idx = t + k*256; int jj = idx>>6, f = idx&63;
      b_s[jj][f] = g_r[(size_t)(jb+jj)*256 + h*64 + f];
    }
    __syncthreads();
    for(int j=0;j<32;j++){
      float4 bv = *(const float4*)&b_s[j][fq*4];
#pragma unroll
      for(int r=0;r<8;r++){
        float av = a_s[iq*8+r][j];
        float pv = p_s[iq*8+r][j];
        accL[r].x = fmaf(av, bv.x, accL[r].x);
        accL[r].y = fmaf(av, bv.y, accL[r].y);
        accL[r].z = fmaf(av, bv.z, accL[r].z);
        accL[r].w = fmaf(av, bv.w, accL[r].w);
        accG[r].x = fmaf(pv, bv.x, accG[r].x);
        accG[r].y = fmaf(pv, bv.y, accG[r].y);
        accG[r].z = fmaf(pv, bv.z, accG[r].z);
        accG[r].w = fmaf(pv, bv.w, accG[r].w);
      }
    }
    __syncthreads();
  }
#pragma unroll
  for(int r=0;r<8;r++){
    int i = i0 + iq*8 + r;
    size_t o = ((size_t)s*N + i)*256 + h*64 + fq*4;
    *(float4*)&partL[o] = accL[r];
    *(float4*)&partG[o] = accG[r];
  }
}

// ---------------- K7: reduce partials + delta-gate epilogue ----------------
__global__ __launch_bounds__(256) void epilogue(const float* __restrict__ partL,
                                                const float* __restrict__ partG,
                                                const int* __restrict__ mask_l,
                                                const float* __restrict__ W_delta,
                                                const float* __restrict__ b_delta,
                                                float* __restrict__ out){
  __shared__ float cat[4][128];
  __shared__ float inter_s[4][64];
  int i = blockIdx.x, t = threadIdx.x;
  int h = t>>6, f = t&63;
  float sl = 0.f, sg = 0.f;
#pragma unroll
  for(int s2=0;s2<8;s2++){
    size_t o = ((size_t)s2*N + i)*256 + h*64 + f;
    sl += partL[o];
    sg += partG[o];
  }
  if(!mask_l[h*N + i]) sl = 0.f;
  cat[h][f]      = sl;
  cat[h][64 + f] = sg;
  __syncthreads();
  float d = b_delta[f];
  for(int c=0;c<128;c++) d = fmaf(cat[h][c], W_delta[(size_t)c*64 + f], d);
  d = (d >= 0.f) ? d : 0.2f*d;
  inter_s[h][f] = d;
  __syncthreads();
  float m = inter_s[0][f];
#pragma unroll
  for(int hh=1;hh<4;hh++) m = fmaxf(m, inter_s[hh][f]);
  float ssum = 0.f;
#pragma unroll
  for(int hh=0;hh<4;hh++) ssum += __expf(inter_s[hh][f]-m);
  float delta = __expf(d - m)/ssum;
  out[(size_t)i*256 + h*64 + f] = delta*sl + (1.f - delta)*sg;
}

// ---------------- launch ----------------
extern "C" void kernel_launch(void* const* d_in, const int* in_sizes, int n_in,
                              void* d_out, int out_size, void* d_ws, size_t ws_size,
                              hipStream_t stream) {
  const float* feats  = (const float*)d_in[0];
  const float* x      = (const float*)d_in[1];
  const int*   adj    = (const int*)  d_in[2];
  const float* W_l    = (const float*)d_in[3];
  const float* W_r    = (const float*)d_in[4];
  const float* attn_w = (const float*)d_in[5];
  const float* W_delta= (const float*)d_in[6];
  const float* b_delta= (const float*)d_in[7];
  float* out = (float*)d_out;

  float* ws = (float*)d_ws;
  size_t off = 0;
  float* g_l   = ws+off; off += (size_t)N*256;       // 262144
  float* g_r   = ws+off; off += (size_t)N*256;
  float* e     = ws+off; off += (size_t)HN*N*N;      // becomes a_1nd
  float* gam   = ws+off; off += (size_t)HN*N*N;
  float* partL = ws+off; off += (size_t)8*N*256;
  float* partG = ws+off; off += (size_t)8*N*256;
  float* pmin_f= ws+off; off += 16*128;
  float* pmax_f= ws+off; off += 16*128;
  float* pmin_g= ws+off; off += 16*256;
  float* pmax_g= ws+off; off += 16*256;
  float* fmn   = ws+off; off += 128;
  float* fmx   = ws+off; off += 128;
  float* gmn   = ws+off; off += 256;
  float* gmx   = ws+off; off += 256;
  float* nf    = ws+off; off += N;
  float* ng    = ws+off; off += (size_t)HN*N;
  float* mgA   = ws+off; off += (size_t)HN*N;
  float* sgA   = ws+off; off += (size_t)HN*N;
  int* mask_l  = (int*)(ws+off); off += (size_t)HN*N;
  int* mask_g  = (int*)(ws+off); off += (size_t)HN*N;

  zero_ints<<<32, 256, 0, stream>>>(mask_l, 2*HN*N);   // mask_l & mask_g contiguous

  gemm_lr<<<128, 256, 0, stream>>>(x, W_l, W_r, g_l, g_r);

  colmm_part<<<dim3(16,2), 256, 0, stream>>>(feats, g_r, pmin_f, pmax_f, pmin_g, pmax_g);
  colmm_fin <<<dim3(2),    256, 0, stream>>>(pmin_f, pmax_f, pmin_g, pmax_g, fmn, fmx, gmn, gmx);
  norms_kernel<<<dim3(N,2),256, 0, stream>>>(feats, g_r, fmn, fmx, gmn, gmx, nf, ng);

  compute_e<<<dim3(16,16,HN), 256, 0, stream>>>(g_l, g_r, attn_w, e);

  row_kernel<<<dim3(N,HN), 256, 0, stream>>>(e, gam, adj, nf, ng, mgA, sgA);

  colselect<<<dim3(N,HN), 256, 0, stream>>>(e,   mask_l);   // e now holds a_1nd
  colselect<<<dim3(N,HN), 256, 0, stream>>>(gam, mask_g);

  attn_mm<<<dim3(8,HN,8), 256, 0, stream>>>(e, gam, g_r, mgA, sgA, mask_g, partL, partG);

  epilogue<<<N, 256, 0, stream>>>(partL, partG, mask_l, W_delta, b_delta, out);
}

// Round 2
// 322.717 us; speedup vs baseline: 1.1835x; 1.1835x over previous
//
#include <hip/hip_runtime.h>
#include <cstdint>
#include <cstddef>

#define N 1024
#define HN 4
#define FDIM 64
#define FLT_MAX_ 3.402823466e+38f

// ---------------- reduction helpers (blockDim.x == 256) ----------------
__device__ __forceinline__ float wred_sum(float v){
#pragma unroll
  for(int o=32;o>0;o>>=1) v += __shfl_down(v,o,64);
  return v;
}
__device__ __forceinline__ float wred_max(float v){
#pragma unroll
  for(int o=32;o>0;o>>=1) v = fmaxf(v,__shfl_down(v,o,64));
  return v;
}
__device__ __forceinline__ float bred_sum(float v, float* scr){
  int t=threadIdx.x;
  v = wred_sum(v);
  __syncthreads();
  if((t&63)==0) scr[t>>6]=v;
  __syncthreads();
  return (scr[0]+scr[1])+(scr[2]+scr[3]);
}
__device__ __forceinline__ float bred_max(float v, float* scr){
  int t=threadIdx.x;
  v = wred_max(v);
  __syncthreads();
  if((t&63)==0) scr[t>>6]=v;
  __syncthreads();
  return fmaxf(fmaxf(scr[0],scr[1]),fmaxf(scr[2],scr[3]));
}

// ---------------- K0: zero masks ----------------
__global__ __launch_bounds__(256) void zero_ints(int* p, int n){
  int i = blockIdx.x*256 + threadIdx.x;
  if(i<n) p[i]=0;
}

// ---------------- K1: g = x@W  (x:[N,256], W:[256,256]); y-dim picks W_l/W_r ----------------
// 4 rows/block, 512 blocks total. x accesses are wave-uniform -> scalar loads;
// W stream is coalesced vector loads, unroll-8 for ILP. Latency-bound fix vs R0.
__global__ __launch_bounds__(256) void gemm_lr(const float* __restrict__ x,
                                               const float* __restrict__ W_l,
                                               const float* __restrict__ W_r,
                                               float* __restrict__ g_l,
                                               float* __restrict__ g_r){
  int i0 = blockIdx.x*4, t = threadIdx.x;
  const float* __restrict__ W = blockIdx.y ? W_r : W_l;
  float* __restrict__ g = blockIdx.y ? g_r : g_l;
  float acc[4] = {0.f,0.f,0.f,0.f};
#pragma unroll 8
  for(int k=0;k<256;k++){
    float w = W[(size_t)k*256 + t];
#pragma unroll
    for(int r=0;r<4;r++) acc[r] = fmaf(x[(size_t)(i0+r)*256 + k], w, acc[r]);
  }
#pragma unroll
  for(int r=0;r<4;r++) g[(size_t)(i0+r)*256 + t] = acc[r];
}

// ---------------- K2p: partial column min/max (16 row-chunks) ----------------
// blockIdx.x = chunk (0..15), blockIdx.y = src (0: feats cols=128, 1: g_r cols=256)
__global__ __launch_bounds__(256) void colmm_part(const float* __restrict__ feats,
                                                  const float* __restrict__ g_r,
                                                  float* __restrict__ pmin_f, float* __restrict__ pmax_f,
                                                  float* __restrict__ pmin_g, float* __restrict__ pmax_g){
  int chunk = blockIdx.x, src = blockIdx.y, t = threadIdx.x;
  int cols = src ? 256 : 128;
  const float* in = src ? g_r : feats;
  if(t < cols){
    float lo = FLT_MAX_, hi = -FLT_MAX_;
    int r0 = chunk*64;
    for(int r=0;r<64;r++){
      float v = in[(size_t)(r0+r)*cols + t];
      lo = fminf(lo,v); hi = fmaxf(hi,v);
    }
    if(src){ pmin_g[chunk*256+t]=lo; pmax_g[chunk*256+t]=hi; }
    else   { pmin_f[chunk*128+t]=lo; pmax_f[chunk*128+t]=hi; }
  }
}

// ---------------- K2f: finalize min/max ----------------
__global__ __launch_bounds__(256) void colmm_fin(const float* __restrict__ pmin_f, const float* __restrict__ pmax_f,
                                                 const float* __restrict__ pmin_g, const float* __restrict__ pmax_g,
                                                 float* __restrict__ fmn, float* __restrict__ fmx,
                                                 float* __restrict__ gmn, float* __restrict__ gmx){
  int src = blockIdx.x, t = threadIdx.x;
  int cols = src ? 256 : 128;
  if(t < cols){
    float lo = FLT_MAX_, hi = -FLT_MAX_;
    const float* pn = src ? pmin_g : pmin_f;
    const float* px = src ? pmax_g : pmax_f;
    for(int k=0;k<16;k++){
      lo = fminf(lo, pn[k*cols+t]);
      hi = fmaxf(hi, px[k*cols+t]);
    }
    if(src){ gmn[t]=lo; gmx[t]=hi; } else { fmn[t]=lo; fmx[t]=hi; }
  }
}

// ---------------- K2n: nf (z=0) and ng (z=1) norms ----------------
__global__ __launch_bounds__(256) void norms_kernel(const float* __restrict__ feats,
                                                    const float* __restrict__ g_r,
                                                    const float* __restrict__ fmn, const float* __restrict__ fmx,
                                                    const float* __restrict__ gmn, const float* __restrict__ gmx,
                                                    float* __restrict__ nf, float* __restrict__ ng){
  __shared__ float scr[4];
  int i = blockIdx.x, z = blockIdx.y, t = threadIdx.x;
  if(z==0){
    float u = 0.f;
    if(t < 128){
      float d = fmx[t]-fmn[t];
      float v = feats[(size_t)i*128 + t];
      u = (d==0.f) ? 0.f : (v - fmn[t])/d;   // matches fn nan-guard
    }
    float tot = bred_sum(u*u, scr);
    if(t==0) nf[i] = sqrtf(tot);
  } else {
    int c = t, hh = t>>6;
    float d = gmx[c]-gmn[c];
    float v = g_r[(size_t)i*256 + c];
    float u = (v - gmn[c])/d;               // reference has no guard here
    float ss = wred_sum(u*u);
    if((t&63)==0) ng[hh*N + i] = sqrtf(ss);
  }
}

// ---------------- K3: e[h][i][j] = sum_f leaky(g_r[i,h,f]+g_l[j,h,f]) * w[f] ----------------
// grid (16,16,4): x=jt, y=it, z=h ; 64x64 tile, 4x4 per thread
__global__ __launch_bounds__(256) void compute_e(const float* __restrict__ g_l,
                                                 const float* __restrict__ g_r,
                                                 const float* __restrict__ attn_w,
                                                 float* __restrict__ e){
  __shared__ float grs[64][65];
  __shared__ float gls[64][65];
  __shared__ float aw[64], aw2[64];
  int h = blockIdx.z, i0 = blockIdx.y*64, j0 = blockIdx.x*64;
  int t = threadIdx.x;
  if(t < 64){ float w = attn_w[t]; aw[t]=w; aw2[t]=0.2f*w; }
#pragma unroll
  for(int k=0;k<16;k++){
    int idx = t + k*256; int r = idx>>6, f = idx&63;
    grs[r][f] = g_r[(size_t)(i0+r)*256 + h*64 + f];
    gls[r][f] = g_l[(size_t)(j0+r)*256 + h*64 + f];
  }
  __syncthreads();
  int tj = t&15, ti = t>>4;       // 16 x 16 thread grid
  float acc[4][4];
#pragma unroll
  for(int a=0;a<4;a++)
#pragma unroll
    for(int b=0;b<4;b++) acc[a][b]=0.f;
  for(int f=0;f<64;f++){
    float w = aw[f], w2 = aw2[f];
    float ga[4], gb[4];
#pragma unroll
    for(int a=0;a<4;a++) ga[a] = grs[ti*4+a][f];
#pragma unroll
    for(int b=0;b<4;b++) gb[b] = gls[tj+16*b][f];
#pragma unroll
    for(int a=0;a<4;a++)
#pragma unroll
      for(int b=0;b<4;b++){
        float s = ga[a]+gb[b];
        float ws = (s >= 0.f) ? w : w2;
        acc[a][b] = fmaf(s, ws, acc[a][b]);
      }
  }
#pragma unroll
  for(int a=0;a<4;a++)
#pragma unroll
    for(int b=0;b<4;b++){
      int i = i0 + ti*4 + a, j = j0 + tj + 16*b;
      e[((size_t)h*N + i)*N + j] = acc[a][b];
    }
}

// ---------------- K4: per-(h,i) row fusion ----------------
// reads e row, writes a_1nd over e, writes gamma, stores m_g/s_g
__global__ __launch_bounds__(256) void row_kernel(float* __restrict__ e,
                                                  float* __restrict__ gam,
                                                  const int* __restrict__ adj,
                                                  const float* __restrict__ nf,
                                                  const float* __restrict__ ng,
                                                  float* __restrict__ mgA,
                                                  float* __restrict__ sgA){
  __shared__ float es[1024];
  __shared__ float nfs[1024];
  __shared__ unsigned char adjs[1024];
  __shared__ float scr[4];
  int i = blockIdx.x, h = blockIdx.y, t = threadIdx.x;
  size_t base = ((size_t)h*N + i)*N;
  float ngv = ng[h*N + i];
#pragma unroll
  for(int k=0;k<4;k++){
    int j = t + k*256;
    es[j]  = e[base + j];
    nfs[j] = nf[j];
    adjs[j] = (adj[(size_t)i*N + j] > 0) ? 1 : 0;
  }
  __syncthreads();
  float ml=-FLT_MAX_, mo=-FLT_MAX_, ma=-FLT_MAX_;
#pragma unroll
  for(int k=0;k<4;k++){
    int j = t + k*256;
    float ev = es[j];
    mo = fmaxf(mo, ev);
    if(adjs[j]) ml = fmaxf(ml, ev);
    ma = fmaxf(ma, fabsf(nfs[j]-ngv));
  }
  ml = bred_max(ml, scr); mo = bred_max(mo, scr); ma = bred_max(ma, scr);
  float sl=0.f, so=0.f, sa=0.f;
#pragma unroll
  for(int k=0;k<4;k++){
    int j = t + k*256;
    float ev = es[j];
    so += __expf(ev-mo);
    if(adjs[j]) sl += __expf(ev-ml);
    sa += __expf(fabsf(nfs[j]-ngv)-ma);
  }
  sl = bred_sum(sl, scr); so = bred_sum(so, scr); sa = bred_sum(sa, scr);
  float isl = 1.f/sl, iso = 1.f/so, isa = 1.f/sa;
  float mg = -FLT_MAX_;
  float gloc[4];
#pragma unroll
  for(int k=0;k<4;k++){
    int j = t + k*256;
    float ev = es[j];
    float omega = __expf(ev-mo)*iso;
    float alpha = __expf(fabsf(nfs[j]-ngv)-ma)*isa;
    float g = 0.5f*(omega + 1.f - alpha);
    gloc[k] = g;
    gam[base+j] = g;
    float a1 = adjs[j] ? __expf(ev-ml)*isl : 0.f;
    e[base+j] = a1;
    mg = fmaxf(mg, g);
  }
  mg = bred_max(mg, scr);
  float sg = 0.f;
#pragma unroll
  for(int k=0;k<4;k++) sg += __expf((gloc[k]-mg)/1e-3f);
  sg = bred_sum(sg, scr);
  if(t==0){ mgA[h*N+i]=mg; sgA[h*N+i]=sg; }
}

// ---------------- K5: exact top-512 column select -> row-union mask ----------------
// grid (N, HN); arr layout [h][i][j]; mask[h*N + i] = 1 if selected in any column
__global__ __launch_bounds__(256) void colselect(const float* __restrict__ arr,
                                                 int* __restrict__ mask){
  __shared__ unsigned int vals[1024];
  __shared__ int hist[256];
  __shared__ int sscan[256];
  __shared__ int bsel, knew, totgt;
  int j = blockIdx.x, h = blockIdx.y, t = threadIdx.x;
  size_t base = ((size_t)h*N)*(size_t)N + j;
#pragma unroll
  for(int q=0;q<4;q++){
    int i = 4*t + q;
    vals[i] = __float_as_uint(arr[base + (size_t)i*N]);  // values >= 0 -> monotone bits
  }
  if(t==0) totgt = 0;
  __syncthreads();
  unsigned prefix = 0; int kth = 512;
  for(int b=3;b>=0;b--){
    hist[t] = 0;
    __syncthreads();
#pragma unroll
    for(int q=0;q<4;q++){
      unsigned u = vals[4*t+q];
      bool act = (b==3) || ((u >> (8*(b+1))) == prefix);
      if(act) atomicAdd(&hist[(u >> (8*b)) & 0xFF], 1);
    }
    __syncthreads();
    sscan[t] = hist[t];
    __syncthreads();
    for(int off=1; off<256; off<<=1){          // inclusive suffix scan
      int v2 = (t+off < 256) ? sscan[t+off] : 0;
      __syncthreads();
      sscan[t] += v2;
      __syncthreads();
    }
    int ge_t  = sscan[t];
    int ge_t1 = ge_t - hist[t];
    if(ge_t >= kth && ge_t1 < kth){ bsel = t; knew = kth - ge_t1; }
    __syncthreads();
    prefix = (prefix << 8) | (unsigned)bsel;
    kth = knew;
    __syncthreads();
  }
  unsigned T = prefix;
  int cg = 0, tc = 0;
#pragma unroll
  for(int q=0;q<4;q++){
    unsigned u = vals[4*t+q];
    cg += (u > T) ? 1 : 0;
    tc += (u == T) ? 1 : 0;
  }
  atomicAdd(&totgt, cg);
  sscan[t] = tc;
  __syncthreads();
  for(int off=1; off<256; off<<=1){            // inclusive prefix scan (index order)
    int v2 = (t >= off) ? sscan[t-off] : 0;
    __syncthreads();
    sscan[t] += v2;
    __syncthreads();
  }
  int tie_excl = sscan[t] - tc;
  __syncthreads();
  int tneed = 512 - totgt;
  int run = tie_excl;
#pragma unroll
  for(int q=0;q<4;q++){
    int i = 4*t+q;
    unsigned u = vals[i];
    bool sel = (u > T);
    if(u == T){ if(run < tneed) sel = true; run++; }
    if(sel) mask[h*N + i] = 1;
  }
}

// ---------------- K6: attn_local / attn_global partial matmuls ----------------
// grid (8, 4, 8): x = i-tile(128 rows), y = h, z = j-split (128 cols of j)
__global__ __launch_bounds__(256) void attn_mm(const float* __restrict__ a1nd,
                                               const float* __restrict__ gam,
                                               const float* __restrict__ g_r,
                                               const float* __restrict__ mgA,
                                               const float* __restrict__ sgA,
                                               const int* __restrict__ mask_g,
                                               float* __restrict__ partL,
                                               float* __restrict__ partG){
  __shared__ __align__(16) float a_s[128][33];
  __shared__ __align__(16) float p_s[128][33];
  __shared__ __align__(16) float b_s[32][64];
  __shared__ float mgv[128], isg[128];
  __shared__ int   mgf[128];
  int i0 = blockIdx.x*128, h = blockIdx.y, s = blockIdx.z, j0 = s*128;
  int t = threadIdx.x;
  if(t < 128){
    mgv[t] = mgA[h*N + i0 + t];
    isg[t] = 1.f / sgA[h*N + i0 + t];
    mgf[t] = mask_g[h*N + i0 + t];
  }
  __syncthreads();
  int fq = t & 15, iq = t >> 4;
  float4 accL[8], accG[8];
#pragma unroll
  for(int r=0;r<8;r++){ accL[r]=make_float4(0,0,0,0); accG[r]=make_float4(0,0,0,0); }
  for(int sub=0; sub<4; sub++){
    int jb = j0 + sub*32;
#pragma unroll
    for(int k=0;k<16;k++){
      int idx = t + k*256; int ii = idx>>5, jj = idx&31;
      size_t g = ((size_t)h*N + i0+ii)*N + jb + jj;
      a_s[ii][jj] = a1nd[g];
      float gm = gam[g];
      p_s[ii][jj] = mgf[ii] ? __expf((gm - mgv[ii])/1e-3f)*isg[ii] : (1.f/1024.f);
    }
#pragma unroll
    for(int k=0;k<8;k++){
      int idx = t + k*256; int jj = idx>>6, f = idx&63;
      b_s[jj][f] = g_r[(size_t)(jb+jj)*256 + h*64 + f];
    }
    __syncthreads();
    for(int j=0;j<32;j++){
      float4 bv = *(const float4*)&b_s[j][fq*4];
#pragma unroll
      for(int r=0;r<8;r++){
        float av = a_s[iq*8+r][j];
        float pv = p_s[iq*8+r][j];
        accL[r].x = fmaf(av, bv.x, accL[r].x);
        accL[r].y = fmaf(av, bv.y, accL[r].y);
        accL[r].z = fmaf(av, bv.z, accL[r].z);
        accL[r].w = fmaf(av, bv.w, accL[r].w);
        accG[r].x = fmaf(pv, bv.x, accG[r].x);
        accG[r].y = fmaf(pv, bv.y, accG[r].y);
        accG[r].z = fmaf(pv, bv.z, accG[r].z);
        accG[r].w = fmaf(pv, bv.w, accG[r].w);
      }
    }
    __syncthreads();
  }
#pragma unroll
  for(int r=0;r<8;r++){
    int i = i0 + iq*8 + r;
    size_t o = ((size_t)s*N + i)*256 + h*64 + fq*4;
    *(float4*)&partL[o] = accL[r];
    *(float4*)&partG[o] = accG[r];
  }
}

// ---------------- K7: reduce partials + delta-gate epilogue ----------------
__global__ __launch_bounds__(256) void epilogue(const float* __restrict__ partL,
                                                const float* __restrict__ partG,
                                                const int* __restrict__ mask_l,
                                                const float* __restrict__ W_delta,
                                                const float* __restrict__ b_delta,
                                                float* __restrict__ out){
  __shared__ float cat[4][128];
  __shared__ float inter_s[4][64];
  int i = blockIdx.x, t = threadIdx.x;
  int h = t>>6, f = t&63;
  float sl = 0.f, sg = 0.f;
#pragma unroll
  for(int s2=0;s2<8;s2++){
    size_t o = ((size_t)s2*N + i)*256 + h*64 + f;
    sl += partL[o];
    sg += partG[o];
  }
  if(!mask_l[h*N + i]) sl = 0.f;
  cat[h][f]      = sl;
  cat[h][64 + f] = sg;
  __syncthreads();
  float d = b_delta[f];
  for(int c=0;c<128;c++) d = fmaf(cat[h][c], W_delta[(size_t)c*64 + f], d);
  d = (d >= 0.f) ? d : 0.2f*d;
  inter_s[h][f] = d;
  __syncthreads();
  float m = inter_s[0][f];
#pragma unroll
  for(int hh=1;hh<4;hh++) m = fmaxf(m, inter_s[hh][f]);
  float ssum = 0.f;
#pragma unroll
  for(int hh=0;hh<4;hh++) ssum += __expf(inter_s[hh][f]-m);
  float delta = __expf(d - m)/ssum;
  out[(size_t)i*256 + h*64 + f] = delta*sl + (1.f - delta)*sg;
}

// ---------------- launch ----------------
extern "C" void kernel_launch(void* const* d_in, const int* in_sizes, int n_in,
                              void* d_out, int out_size, void* d_ws, size_t ws_size,
                              hipStream_t stream) {
  const float* feats  = (const float*)d_in[0];
  const float* x      = (const float*)d_in[1];
  const int*   adj    = (const int*)  d_in[2];
  const float* W_l    = (const float*)d_in[3];
  const float* W_r    = (const float*)d_in[4];
  const float* attn_w = (const float*)d_in[5];
  const float* W_delta= (const float*)d_in[6];
  const float* b_delta= (const float*)d_in[7];
  float* out = (float*)d_out;

  float* ws = (float*)d_ws;
  size_t off = 0;
  float* g_l   = ws+off; off += (size_t)N*256;       // 262144
  float* g_r   = ws+off; off += (size_t)N*256;
  float* e     = ws+off; off += (size_t)HN*N*N;      // becomes a_1nd
  float* gam   = ws+off; off += (size_t)HN*N*N;
  float* partL = ws+off; off += (size_t)8*N*256;
  float* partG = ws+off; off += (size_t)8*N*256;
  float* pmin_f= ws+off; off += 16*128;
  float* pmax_f= ws+off; off += 16*128;
  float* pmin_g= ws+off; off += 16*256;
  float* pmax_g= ws+off; off += 16*256;
  float* fmn   = ws+off; off += 128;
  float* fmx   = ws+off; off += 128;
  float* gmn   = ws+off; off += 256;
  float* gmx   = ws+off; off += 256;
  float* nf    = ws+off; off += N;
  float* ng    = ws+off; off += (size_t)HN*N;
  float* mgA   = ws+off; off += (size_t)HN*N;
  float* sgA   = ws+off; off += (size_t)HN*N;
  int* mask_l  = (int*)(ws+off); off += (size_t)HN*N;
  int* mask_g  = (int*)(ws+off); off += (size_t)HN*N;

  zero_ints<<<32, 256, 0, stream>>>(mask_l, 2*HN*N);   // mask_l & mask_g contiguous

  gemm_lr<<<dim3(256,2), 256, 0, stream>>>(x, W_l, W_r, g_l, g_r);

  colmm_part<<<dim3(16,2), 256, 0, stream>>>(feats, g_r, pmin_f, pmax_f, pmin_g, pmax_g);
  colmm_fin <<<dim3(2),    256, 0, stream>>>(pmin_f, pmax_f, pmin_g, pmax_g, fmn, fmx, gmn, gmx);
  norms_kernel<<<dim3(N,2),256, 0, stream>>>(feats, g_r, fmn, fmx, gmn, gmx, nf, ng);

  compute_e<<<dim3(16,16,HN), 256, 0, stream>>>(g_l, g_r, attn_w, e);

  row_kernel<<<dim3(N,HN), 256, 0, stream>>>(e, gam, adj, nf, ng, mgA, sgA);

  colselect<<<dim3(N,HN), 256, 0, stream>>>(e,   mask_l);   // e now holds a_1nd
  colselect<<<dim3(N,HN), 256, 0, stream>>>(gam, mask_g);

  attn_mm<<<dim3(8,HN,8), 256, 0, stream>>>(e, gam, g_r, mgA, sgA, mask_g, partL, partG);

  epilogue<<<N, 256, 0, stream>>>(partL, partG, mask_l, W_delta, b_delta, out);
}

// Round 3
// 275.887 us; speedup vs baseline: 1.3844x; 1.1697x over previous
//
#include <hip/hip_runtime.h>
#include <cstdint>
#include <cstddef>

#define N 1024
#define HN 4
#define FDIM 64
#define FLT_MAX_ 3.402823466e+38f

// ---------------- reduction helpers (blockDim.x == 256) ----------------
__device__ __forceinline__ float wred_sum(float v){
#pragma unroll
  for(int o=32;o>0;o>>=1) v += __shfl_down(v,o,64);
  return v;
}
__device__ __forceinline__ float wred_max(float v){
#pragma unroll
  for(int o=32;o>0;o>>=1) v = fmaxf(v,__shfl_down(v,o,64));
  return v;
}
__device__ __forceinline__ float bred_sum(float v, float* scr){
  int t=threadIdx.x;
  v = wred_sum(v);
  __syncthreads();
  if((t&63)==0) scr[t>>6]=v;
  __syncthreads();
  return (scr[0]+scr[1])+(scr[2]+scr[3]);
}
__device__ __forceinline__ float bred_max(float v, float* scr){
  int t=threadIdx.x;
  v = wred_max(v);
  __syncthreads();
  if((t&63)==0) scr[t>>6]=v;
  __syncthreads();
  return fmaxf(fmaxf(scr[0],scr[1]),fmaxf(scr[2],scr[3]));
}

// ---------------- K0: zero masks ----------------
__global__ __launch_bounds__(256) void zero_ints(int* p, int n){
  int i = blockIdx.x*256 + threadIdx.x;
  if(i<n) p[i]=0;
}

// ---------------- K1: g = x@W ----------------
__global__ __launch_bounds__(256) void gemm_lr(const float* __restrict__ x,
                                               const float* __restrict__ W_l,
                                               const float* __restrict__ W_r,
                                               float* __restrict__ g_l,
                                               float* __restrict__ g_r){
  int i0 = blockIdx.x*4, t = threadIdx.x;
  const float* __restrict__ W = blockIdx.y ? W_r : W_l;
  float* __restrict__ g = blockIdx.y ? g_r : g_l;
  float acc[4] = {0.f,0.f,0.f,0.f};
#pragma unroll 8
  for(int k=0;k<256;k++){
    float w = W[(size_t)k*256 + t];
#pragma unroll
    for(int r=0;r<4;r++) acc[r] = fmaf(x[(size_t)(i0+r)*256 + k], w, acc[r]);
  }
#pragma unroll
  for(int r=0;r<4;r++) g[(size_t)(i0+r)*256 + t] = acc[r];
}

// ---------------- K2p/K2f/K2n: min/max + norms ----------------
__global__ __launch_bounds__(256) void colmm_part(const float* __restrict__ feats,
                                                  const float* __restrict__ g_r,
                                                  float* __restrict__ pmin_f, float* __restrict__ pmax_f,
                                                  float* __restrict__ pmin_g, float* __restrict__ pmax_g){
  int chunk = blockIdx.x, src = blockIdx.y, t = threadIdx.x;
  int cols = src ? 256 : 128;
  const float* in = src ? g_r : feats;
  if(t < cols){
    float lo = FLT_MAX_, hi = -FLT_MAX_;
    int r0 = chunk*64;
    for(int r=0;r<64;r++){
      float v = in[(size_t)(r0+r)*cols + t];
      lo = fminf(lo,v); hi = fmaxf(hi,v);
    }
    if(src){ pmin_g[chunk*256+t]=lo; pmax_g[chunk*256+t]=hi; }
    else   { pmin_f[chunk*128+t]=lo; pmax_f[chunk*128+t]=hi; }
  }
}

__global__ __launch_bounds__(256) void colmm_fin(const float* __restrict__ pmin_f, const float* __restrict__ pmax_f,
                                                 const float* __restrict__ pmin_g, const float* __restrict__ pmax_g,
                                                 float* __restrict__ fmn, float* __restrict__ fmx,
                                                 float* __restrict__ gmn, float* __restrict__ gmx){
  int src = blockIdx.x, t = threadIdx.x;
  int cols = src ? 256 : 128;
  if(t < cols){
    float lo = FLT_MAX_, hi = -FLT_MAX_;
    const float* pn = src ? pmin_g : pmin_f;
    const float* px = src ? pmax_g : pmax_f;
    for(int k=0;k<16;k++){
      lo = fminf(lo, pn[k*cols+t]);
      hi = fmaxf(hi, px[k*cols+t]);
    }
    if(src){ gmn[t]=lo; gmx[t]=hi; } else { fmn[t]=lo; fmx[t]=hi; }
  }
}

__global__ __launch_bounds__(256) void norms_kernel(const float* __restrict__ feats,
                                                    const float* __restrict__ g_r,
                                                    const float* __restrict__ fmn, const float* __restrict__ fmx,
                                                    const float* __restrict__ gmn, const float* __restrict__ gmx,
                                                    float* __restrict__ nf, float* __restrict__ ng){
  __shared__ float scr[4];
  int i = blockIdx.x, z = blockIdx.y, t = threadIdx.x;
  if(z==0){
    float u = 0.f;
    if(t < 128){
      float d = fmx[t]-fmn[t];
      float v = feats[(size_t)i*128 + t];
      u = (d==0.f) ? 0.f : (v - fmn[t])/d;
    }
    float tot = bred_sum(u*u, scr);
    if(t==0) nf[i] = sqrtf(tot);
  } else {
    int c = t, hh = t>>6;
    float d = gmx[c]-gmn[c];
    float v = g_r[(size_t)i*256 + c];
    float u = (v - gmn[c])/d;
    float ss = wred_sum(u*u);
    if((t&63)==0) ng[hh*N + i] = sqrtf(ss);
  }
}

// ---------------- K3: e[h][i][j] ----------------
__global__ __launch_bounds__(256) void compute_e(const float* __restrict__ g_l,
                                                 const float* __restrict__ g_r,
                                                 const float* __restrict__ attn_w,
                                                 float* __restrict__ e){
  __shared__ float grs[64][65];
  __shared__ float gls[64][65];
  __shared__ float aw[64], aw2[64];
  int h = blockIdx.z, i0 = blockIdx.y*64, j0 = blockIdx.x*64;
  int t = threadIdx.x;
  if(t < 64){ float w = attn_w[t]; aw[t]=w; aw2[t]=0.2f*w; }
#pragma unroll
  for(int k=0;k<16;k++){
    int idx = t + k*256; int r = idx>>6, f = idx&63;
    grs[r][f] = g_r[(size_t)(i0+r)*256 + h*64 + f];
    gls[r][f] = g_l[(size_t)(j0+r)*256 + h*64 + f];
  }
  __syncthreads();
  int tj = t&15, ti = t>>4;
  float acc[4][4];
#pragma unroll
  for(int a=0;a<4;a++)
#pragma unroll
    for(int b=0;b<4;b++) acc[a][b]=0.f;
  for(int f=0;f<64;f++){
    float w = aw[f], w2 = aw2[f];
    float ga[4], gb[4];
#pragma unroll
    for(int a=0;a<4;a++) ga[a] = grs[ti*4+a][f];
#pragma unroll
    for(int b=0;b<4;b++) gb[b] = gls[tj+16*b][f];
#pragma unroll
    for(int a=0;a<4;a++)
#pragma unroll
      for(int b=0;b<4;b++){
        float s = ga[a]+gb[b];
        float ws = (s >= 0.f) ? w : w2;
        acc[a][b] = fmaf(s, ws, acc[a][b]);
      }
  }
#pragma unroll
  for(int a=0;a<4;a++)
#pragma unroll
    for(int b=0;b<4;b++){
      int i = i0 + ti*4 + a, j = j0 + tj + 16*b;
      e[((size_t)h*N + i)*N + j] = acc[a][b];
    }
}

// ---------------- K4: per-(h,i) row fusion ----------------
__global__ __launch_bounds__(256) void row_kernel(float* __restrict__ e,
                                                  float* __restrict__ gam,
                                                  const int* __restrict__ adj,
                                                  const float* __restrict__ nf,
                                                  const float* __restrict__ ng,
                                                  float* __restrict__ mgA,
                                                  float* __restrict__ sgA){
  __shared__ float es[1024];
  __shared__ float nfs[1024];
  __shared__ unsigned char adjs[1024];
  __shared__ float scr[4];
  int i = blockIdx.x, h = blockIdx.y, t = threadIdx.x;
  size_t base = ((size_t)h*N + i)*N;
  float ngv = ng[h*N + i];
#pragma unroll
  for(int k=0;k<4;k++){
    int j = t + k*256;
    es[j]  = e[base + j];
    nfs[j] = nf[j];
    adjs[j] = (adj[(size_t)i*N + j] > 0) ? 1 : 0;
  }
  __syncthreads();
  float ml=-FLT_MAX_, mo=-FLT_MAX_, ma=-FLT_MAX_;
#pragma unroll
  for(int k=0;k<4;k++){
    int j = t + k*256;
    float ev = es[j];
    mo = fmaxf(mo, ev);
    if(adjs[j]) ml = fmaxf(ml, ev);
    ma = fmaxf(ma, fabsf(nfs[j]-ngv));
  }
  ml = bred_max(ml, scr); mo = bred_max(mo, scr); ma = bred_max(ma, scr);
  float sl=0.f, so=0.f, sa=0.f;
#pragma unroll
  for(int k=0;k<4;k++){
    int j = t + k*256;
    float ev = es[j];
    so += __expf(ev-mo);
    if(adjs[j]) sl += __expf(ev-ml);
    sa += __expf(fabsf(nfs[j]-ngv)-ma);
  }
  sl = bred_sum(sl, scr); so = bred_sum(so, scr); sa = bred_sum(sa, scr);
  float isl = 1.f/sl, iso = 1.f/so, isa = 1.f/sa;
  float mg = -FLT_MAX_;
  float gloc[4];
#pragma unroll
  for(int k=0;k<4;k++){
    int j = t + k*256;
    float ev = es[j];
    float omega = __expf(ev-mo)*iso;
    float alpha = __expf(fabsf(nfs[j]-ngv)-ma)*isa;
    float g = 0.5f*(omega + 1.f - alpha);
    gloc[k] = g;
    gam[base+j] = g;
    float a1 = adjs[j] ? __expf(ev-ml)*isl : 0.f;
    e[base+j] = a1;
    mg = fmaxf(mg, g);
  }
  mg = bred_max(mg, scr);
  float sg = 0.f;
#pragma unroll
  for(int k=0;k<4;k++) sg += __expf((gloc[k]-mg)/1e-3f);
  sg = bred_sum(sg, scr);
  if(t==0){ mgA[h*N+i]=mg; sgA[h*N+i]=sg; }
}

// ---------------- K5: exact top-512 column select -> row-union mask ----------------
// wave-shuffle scans + per-wave split histograms (low sync count, low atomic serialization)
__global__ __launch_bounds__(256) void colselect(const float* __restrict__ arr,
                                                 int* __restrict__ mask){
  __shared__ unsigned int vals[1024];
  __shared__ int hist4[4][256];
  __shared__ int wtot[4];
  __shared__ int bsel_s, knew_s, totgt;
  int j = blockIdx.x, h = blockIdx.y, t = threadIdx.x;
  int lane = t & 63, w = t >> 6;
  size_t base = ((size_t)h*N)*(size_t)N + j;
#pragma unroll
  for(int q=0;q<4;q++){
    int i = 4*t + q;
    vals[i] = __float_as_uint(arr[base + (size_t)i*N]);  // values >= 0 -> monotone bits
  }
  __syncthreads();
  unsigned prefix = 0; int kth = 512;
  for(int b=3;b>=0;b--){
#pragma unroll
    for(int ww=0;ww<4;ww++) hist4[ww][t]=0;
    __syncthreads();
#pragma unroll
    for(int q=0;q<4;q++){
      unsigned u = vals[4*t+q];
      bool act = (b==3) || ((u >> (8*(b+1))) == prefix);
      if(act) atomicAdd(&hist4[w][(u >> (8*b)) & 0xFF], 1);
    }
    __syncthreads();
    int u255 = 255 - t;
    int hv = hist4[0][u255]+hist4[1][u255]+hist4[2][u255]+hist4[3][u255];
    int p = hv;
#pragma unroll
    for(int off=1; off<64; off<<=1){
      int q2 = __shfl_up(p, off, 64);
      if(lane >= off) p += q2;
    }
    if(lane==63) wtot[w] = p;
    __syncthreads();
    int add = 0;
#pragma unroll
    for(int ww=0;ww<4;ww++) if(ww < w) add += wtot[ww];
    int ge = p + add, ge1 = ge - hv;
    if(ge >= kth && ge1 < kth){ bsel_s = u255; knew_s = kth - ge1; }
    __syncthreads();
    prefix = (prefix << 8) | (unsigned)bsel_s;
    kth = knew_s;
    __syncthreads();
  }
  unsigned T = prefix;
  if(t==0) totgt = 0;
  __syncthreads();
  int cg = 0, tc = 0;
#pragma unroll
  for(int q=0;q<4;q++){
    unsigned u = vals[4*t+q];
    cg += (u > T) ? 1 : 0;
    tc += (u == T) ? 1 : 0;
  }
  int cgw = cg;
#pragma unroll
  for(int o=32;o>0;o>>=1) cgw += __shfl_down(cgw,o,64);
  if(lane==0) atomicAdd(&totgt, cgw);
  int pc = tc;
#pragma unroll
  for(int off=1; off<64; off<<=1){
    int q2 = __shfl_up(pc, off, 64);
    if(lane >= off) pc += q2;
  }
  if(lane==63) wtot[w] = pc;
  __syncthreads();
  int add = 0;
#pragma unroll
  for(int ww=0;ww<4;ww++) if(ww < w) add += wtot[ww];
  pc += add;
  int tie_excl = pc - tc;
  int tneed = 512 - totgt;
  int run = tie_excl;
#pragma unroll
  for(int q=0;q<4;q++){
    int i = 4*t+q;
    unsigned u = vals[i];
    bool sel = (u > T);
    if(u == T){ if(run < tneed) sel = true; run++; }
    if(sel) mask[h*N + i] = 1;
  }
}

// ---------------- K5b: prep P = temp-softmax(gamma) in place ----------------
// grid (N, HN). Must run AFTER colselect(gam).
__global__ __launch_bounds__(256) void prep_p(float* __restrict__ gam,
                                              const float* __restrict__ mgA,
                                              const float* __restrict__ sgA,
                                              const int* __restrict__ mask_g){
  int i = blockIdx.x, h = blockIdx.y, t = threadIdx.x;
  size_t base = ((size_t)h*N + i)*N;
  float mg = mgA[h*N+i];
  float isg = 1.f/sgA[h*N+i];
  int m = mask_g[h*N+i];
  float4* g4 = (float4*)(gam + base);
  float4 v = g4[t];
  if(m){
    v.x = __expf((v.x-mg)/1e-3f)*isg;
    v.y = __expf((v.y-mg)/1e-3f)*isg;
    v.z = __expf((v.z-mg)/1e-3f)*isg;
    v.w = __expf((v.w-mg)/1e-3f)*isg;
  } else {
    const float inv = 1.f/1024.f;
    v = make_float4(inv,inv,inv,inv);
  }
  g4[t] = v;
}

// ---------------- K6: attn_local / attn_global partial matmuls ----------------
// grid (16, 4, 8): x = i-tile (64 rows), y = h, z = j-split (128 cols).
// A/P staged transposed in LDS -> inner loop is 3x ds_read_b128 + 32 FMA per j.
__global__ __launch_bounds__(256) void attn_mm(const float* __restrict__ a1nd,
                                               const float* __restrict__ p,
                                               const float* __restrict__ g_r,
                                               float* __restrict__ partL,
                                               float* __restrict__ partG){
  __shared__ __align__(16) float a_t[32][68];
  __shared__ __align__(16) float p_t[32][68];
  __shared__ __align__(16) float b_s[32][68];
  int i0 = blockIdx.x*64, h = blockIdx.y, s = blockIdx.z, j0 = s*128;
  int t = threadIdx.x;
  int fq = t & 15, iq = t >> 4;
  float4 accL[4], accG[4];
#pragma unroll
  for(int r=0;r<4;r++){ accL[r]=make_float4(0,0,0,0); accG[r]=make_float4(0,0,0,0); }
  size_t abase = ((size_t)h*N + i0)*N;
  for(int sub=0; sub<4; sub++){
    int jb = j0 + sub*32;
#pragma unroll
    for(int k=0;k<2;k++){
      int idx = t + k*256;
      int row = idx>>3, c4 = idx&7;
      float4 va = *(const float4*)(a1nd + abase + (size_t)row*N + jb + c4*4);
      float4 vp = *(const float4*)(p    + abase + (size_t)row*N + jb + c4*4);
      a_t[c4*4+0][row]=va.x; a_t[c4*4+1][row]=va.y; a_t[c4*4+2][row]=va.z; a_t[c4*4+3][row]=va.w;
      p_t[c4*4+0][row]=vp.x; p_t[c4*4+1][row]=vp.y; p_t[c4*4+2][row]=vp.z; p_t[c4*4+3][row]=vp.w;
      int rj = idx>>4, d4 = idx&15;
      *(float4*)&b_s[rj][d4*4] = *(const float4*)(g_r + (size_t)(jb+rj)*256 + h*64 + d4*4);
    }
    __syncthreads();
#pragma unroll 4
    for(int j=0;j<32;j++){
      float4 bv = *(float4*)&b_s[j][fq*4];
      float4 av = *(float4*)&a_t[j][iq*4];
      float4 pv = *(float4*)&p_t[j][iq*4];
      accL[0].x = fmaf(av.x, bv.x, accL[0].x); accL[0].y = fmaf(av.x, bv.y, accL[0].y);
      accL[0].z = fmaf(av.x, bv.z, accL[0].z); accL[0].w = fmaf(av.x, bv.w, accL[0].w);
      accL[1].x = fmaf(av.y, bv.x, accL[1].x); accL[1].y = fmaf(av.y, bv.y, accL[1].y);
      accL[1].z = fmaf(av.y, bv.z, accL[1].z); accL[1].w = fmaf(av.y, bv.w, accL[1].w);
      accL[2].x = fmaf(av.z, bv.x, accL[2].x); accL[2].y = fmaf(av.z, bv.y, accL[2].y);
      accL[2].z = fmaf(av.z, bv.z, accL[2].z); accL[2].w = fmaf(av.z, bv.w, accL[2].w);
      accL[3].x = fmaf(av.w, bv.x, accL[3].x); accL[3].y = fmaf(av.w, bv.y, accL[3].y);
      accL[3].z = fmaf(av.w, bv.z, accL[3].z); accL[3].w = fmaf(av.w, bv.w, accL[3].w);
      accG[0].x = fmaf(pv.x, bv.x, accG[0].x); accG[0].y = fmaf(pv.x, bv.y, accG[0].y);
      accG[0].z = fmaf(pv.x, bv.z, accG[0].z); accG[0].w = fmaf(pv.x, bv.w, accG[0].w);
      accG[1].x = fmaf(pv.y, bv.x, accG[1].x); accG[1].y = fmaf(pv.y, bv.y, accG[1].y);
      accG[1].z = fmaf(pv.y, bv.z, accG[1].z); accG[1].w = fmaf(pv.y, bv.w, accG[1].w);
      accG[2].x = fmaf(pv.z, bv.x, accG[2].x); accG[2].y = fmaf(pv.z, bv.y, accG[2].y);
      accG[2].z = fmaf(pv.z, bv.z, accG[2].z); accG[2].w = fmaf(pv.z, bv.w, accG[2].w);
      accG[3].x = fmaf(pv.w, bv.x, accG[3].x); accG[3].y = fmaf(pv.w, bv.y, accG[3].y);
      accG[3].z = fmaf(pv.w, bv.z, accG[3].z); accG[3].w = fmaf(pv.w, bv.w, accG[3].w);
    }
    __syncthreads();
  }
#pragma unroll
  for(int r=0;r<4;r++){
    int i = i0 + iq*4 + r;
    size_t o = ((size_t)s*N + i)*256 + h*64 + fq*4;
    *(float4*)&partL[o] = accL[r];
    *(float4*)&partG[o] = accG[r];
  }
}

// ---------------- K7: reduce partials + delta-gate epilogue ----------------
__global__ __launch_bounds__(256) void epilogue(const float* __restrict__ partL,
                                                const float* __restrict__ partG,
                                                const int* __restrict__ mask_l,
                                                const float* __restrict__ W_delta,
                                                const float* __restrict__ b_delta,
                                                float* __restrict__ out){
  __shared__ float cat[4][128];
  __shared__ float inter_s[4][64];
  int i = blockIdx.x, t = threadIdx.x;
  int h = t>>6, f = t&63;
  float sl = 0.f, sg = 0.f;
#pragma unroll
  for(int s2=0;s2<8;s2++){
    size_t o = ((size_t)s2*N + i)*256 + h*64 + f;
    sl += partL[o];
    sg += partG[o];
  }
  if(!mask_l[h*N + i]) sl = 0.f;
  cat[h][f]      = sl;
  cat[h][64 + f] = sg;
  __syncthreads();
  float d = b_delta[f];
  for(int c=0;c<128;c++) d = fmaf(cat[h][c], W_delta[(size_t)c*64 + f], d);
  d = (d >= 0.f) ? d : 0.2f*d;
  inter_s[h][f] = d;
  __syncthreads();
  float m = inter_s[0][f];
#pragma unroll
  for(int hh=1;hh<4;hh++) m = fmaxf(m, inter_s[hh][f]);
  float ssum = 0.f;
#pragma unroll
  for(int hh=0;hh<4;hh++) ssum += __expf(inter_s[hh][f]-m);
  float delta = __expf(d - m)/ssum;
  out[(size_t)i*256 + h*64 + f] = delta*sl + (1.f - delta)*sg;
}

// ---------------- launch ----------------
extern "C" void kernel_launch(void* const* d_in, const int* in_sizes, int n_in,
                              void* d_out, int out_size, void* d_ws, size_t ws_size,
                              hipStream_t stream) {
  const float* feats  = (const float*)d_in[0];
  const float* x      = (const float*)d_in[1];
  const int*   adj    = (const int*)  d_in[2];
  const float* W_l    = (const float*)d_in[3];
  const float* W_r    = (const float*)d_in[4];
  const float* attn_w = (const float*)d_in[5];
  const float* W_delta= (const float*)d_in[6];
  const float* b_delta= (const float*)d_in[7];
  float* out = (float*)d_out;

  float* ws = (float*)d_ws;
  size_t off = 0;
  float* g_l   = ws+off; off += (size_t)N*256;
  float* g_r   = ws+off; off += (size_t)N*256;
  float* e     = ws+off; off += (size_t)HN*N*N;      // becomes a_1nd
  float* gam   = ws+off; off += (size_t)HN*N*N;      // becomes P after prep_p
  float* partL = ws+off; off += (size_t)8*N*256;
  float* partG = ws+off; off += (size_t)8*N*256;
  float* pmin_f= ws+off; off += 16*128;
  float* pmax_f= ws+off; off += 16*128;
  float* pmin_g= ws+off; off += 16*256;
  float* pmax_g= ws+off; off += 16*256;
  float* fmn   = ws+off; off += 128;
  float* fmx   = ws+off; off += 128;
  float* gmn   = ws+off; off += 256;
  float* gmx   = ws+off; off += 256;
  float* nf    = ws+off; off += N;
  float* ng    = ws+off; off += (size_t)HN*N;
  float* mgA   = ws+off; off += (size_t)HN*N;
  float* sgA   = ws+off; off += (size_t)HN*N;
  int* mask_l  = (int*)(ws+off); off += (size_t)HN*N;
  int* mask_g  = (int*)(ws+off); off += (size_t)HN*N;

  zero_ints<<<32, 256, 0, stream>>>(mask_l, 2*HN*N);

  gemm_lr<<<dim3(256,2), 256, 0, stream>>>(x, W_l, W_r, g_l, g_r);

  colmm_part<<<dim3(16,2), 256, 0, stream>>>(feats, g_r, pmin_f, pmax_f, pmin_g, pmax_g);
  colmm_fin <<<dim3(2),    256, 0, stream>>>(pmin_f, pmax_f, pmin_g, pmax_g, fmn, fmx, gmn, gmx);
  norms_kernel<<<dim3(N,2),256, 0, stream>>>(feats, g_r, fmn, fmx, gmn, gmx, nf, ng);

  compute_e<<<dim3(16,16,HN), 256, 0, stream>>>(g_l, g_r, attn_w, e);

  row_kernel<<<dim3(N,HN), 256, 0, stream>>>(e, gam, adj, nf, ng, mgA, sgA);

  colselect<<<dim3(N,HN), 256, 0, stream>>>(e,   mask_l);   // e now holds a_1nd
  colselect<<<dim3(N,HN), 256, 0, stream>>>(gam, mask_g);

  prep_p<<<dim3(N,HN), 256, 0, stream>>>(gam, mgA, sgA, mask_g);

  attn_mm<<<dim3(16,HN,8), 256, 0, stream>>>(e, gam, g_r, partL, partG);

  epilogue<<<N, 256, 0, stream>>>(partL, partG, mask_l, W_delta, b_delta, out);
}